// Round 1
// baseline (277.292 us; speedup 1.0000x reference)
//
#include <hip/hip_runtime.h>
#include <math.h>

#define T_FRAMES 16384
#define FDIM 2048
#define LQ 30

// ---------------------------------------------------------------------------
// Kernel 0: precompute per-head 7x7 bilinear forms
//   A_h[c][c2] = sum_d W_q[h*64+d][c] * W_k[h*64+d][c2]
//   M_h[c][c2] = sum_d W_o[c][h*64+d] * W_v[h*64+d][c2]
// AM layout: [0..195] = A (h*49 + c*7 + c2), [196..391] = M
// ---------------------------------------------------------------------------
__global__ __launch_bounds__(448) void setup_kernel(
    const float* __restrict__ Wq, const float* __restrict__ Wk,
    const float* __restrict__ Wv, const float* __restrict__ Wo,
    float* __restrict__ AM) {
  const int e = threadIdx.x;
  if (e >= 392) return;
  const int which = e / 196;
  const int r = e % 196;
  const int h = r / 49;
  const int rr = r % 49;
  const int c = rr / 7;
  const int c2 = rr % 7;
  float s = 0.0f;
  if (which == 0) {
    for (int d = 0; d < 64; ++d)
      s = fmaf(Wq[(h * 64 + d) * 7 + c], Wk[(h * 64 + d) * 7 + c2], s);
  } else {
    for (int d = 0; d < 64; ++d)
      s = fmaf(Wo[c * 256 + h * 64 + d], Wv[(h * 64 + d) * 7 + c2], s);
  }
  AM[e] = s;
}

// ---------------------------------------------------------------------------
// Kernel 1: feas[t][c] = tanh(lf[t] . Wfc[c])   -- pure streaming GEMV
// Each wave owns FR=2 frames; issues ALL 16 float4 lf loads up front
// (16 KB in flight per wave) before any FMA -> deep vmcnt queue.
// Wfc chunk loads (L1/L2-hot) interleave with the FMA phase.
// Result written to `feas` (= out buffer, reused as scratch).
// ---------------------------------------------------------------------------
#define FPB_A 8   // frames per block: 4 waves x 2 frames

__global__ __launch_bounds__(256) void feas_kernel(
    const float* __restrict__ lf,    // (T, 2048)
    const float* __restrict__ Wfc,   // (7, 2048)
    float* __restrict__ feas) {      // (T, 7)
  const int tid = threadIdx.x;
  const int lane = tid & 63;
  const int wave = tid >> 6;
  const int t0 = blockIdx.x * FPB_A + wave * 2;   // frames t0, t0+1
  const float* lfp = lf + (size_t)t0 * FDIM + lane * 4;

  // burst-load both full rows: 16 independent float4 loads per lane
  float4 a0[8], a1[8];
#pragma unroll
  for (int ch = 0; ch < 8; ++ch) a0[ch] = *(const float4*)(lfp + ch * 256);
#pragma unroll
  for (int ch = 0; ch < 8; ++ch) a1[ch] = *(const float4*)(lfp + FDIM + ch * 256);

  float acc0[7] = {0, 0, 0, 0, 0, 0, 0};
  float acc1[7] = {0, 0, 0, 0, 0, 0, 0};
#pragma unroll
  for (int ch = 0; ch < 8; ++ch) {
#pragma unroll
    for (int c = 0; c < 7; ++c) {
      const float4 w = *(const float4*)(Wfc + c * FDIM + ch * 256 + lane * 4);
      acc0[c] = fmaf(a0[ch].x, w.x, fmaf(a0[ch].y, w.y,
                fmaf(a0[ch].z, w.z, fmaf(a0[ch].w, w.w, acc0[c]))));
      acc1[c] = fmaf(a1[ch].x, w.x, fmaf(a1[ch].y, w.y,
                fmaf(a1[ch].z, w.z, fmaf(a1[ch].w, w.w, acc1[c]))));
    }
  }

  // cross-lane reduce (64 lanes) + tanh + store
#pragma unroll
  for (int c = 0; c < 7; ++c) {
    float v0 = acc0[c];
    float v1 = acc1[c];
#pragma unroll
    for (int off = 32; off > 0; off >>= 1) {
      v0 += __shfl_down(v0, off, 64);
      v1 += __shfl_down(v1, off, 64);
    }
    if (lane == 0) {
      feas[(size_t)t0 * 7 + c]       = tanhf(v0);
      feas[(size_t)(t0 + 1) * 7 + c] = tanhf(v1);
    }
  }
}

// ---------------------------------------------------------------------------
// Kernel 2: attention + FFN + LNs. 64 frames/block, 256 threads:
//   2a: thread = (frame, head) -> ALL 256 threads active
//   2b: one lane per frame epilogue
// Reads feas from `out`, overwrites `out` in place (LDS-staged before barrier;
// each block touches only its own 64 frames -> no cross-block hazard).
// ---------------------------------------------------------------------------
#define BF 64   // frames per block

__global__ __launch_bounds__(256) void attn_kernel(
    const float* __restrict__ x,       // (7, T)
    const float* __restrict__ feas_g,  // (T, 7)  == out
    const float* __restrict__ AM,      // 392
    const float* __restrict__ W1,      // (64, 7)
    const float* __restrict__ W2,      // (7, 64)
    const float* __restrict__ ln1g, const float* __restrict__ ln1b,
    const float* __restrict__ ln2g, const float* __restrict__ ln2b,
    float* __restrict__ out) {         // (T, 7)
  __shared__ float AM_s[392];
  __shared__ float ft[(BF + LQ - 1) * 7];   // 93 rows x 7, row r = frame t0-29+r
  __shared__ float feas_s[BF][7];
  __shared__ float hpart[BF][4][7];

  const int tid = threadIdx.x;
  const int t0 = blockIdx.x * BF;

  for (int i = tid; i < 392; i += 256) AM_s[i] = AM[i];
  for (int i = tid; i < (BF + LQ - 1) * 7; i += 256) {
    const int row = i / 7, c = i % 7;
    const int s = t0 - (LQ - 1) + row;
    ft[i] = (s >= 0) ? x[c * T_FRAMES + s] : 0.0f;
  }
  for (int i = tid; i < BF * 7; i += 256)
    feas_s[i / 7][i % 7] = feas_g[(size_t)t0 * 7 + i];
  __syncthreads();

  // ---- phase 2a: (frame, head) per thread, 256/256 active ----
  {
    const int f = tid >> 2;   // local frame 0..63
    const int h = tid & 3;    // head
    float fe[7];
#pragma unroll
    for (int c = 0; c < 7; ++c) fe[c] = feas_s[f][c];

    const float* Ah = AM_s + h * 49;
    const float* Mh = AM_s + 196 + h * 49;
    float qk[7];
#pragma unroll
    for (int c2 = 0; c2 < 7; ++c2) {
      float s = 0.0f;
#pragma unroll
      for (int c = 0; c < 7; ++c) s = fmaf(fe[c], Ah[c * 7 + c2], s);
      qk[c2] = s * 0.125f;
    }
    // window rows for frame f are ft[(f+j)*7 + c], j = 0..29
    const float* frow = &ft[f * 7];
    float sc[LQ];
    float m = -1e30f;
#pragma unroll
    for (int j = 0; j < LQ; ++j) {
      const float* r = frow + j * 7;
      float s = 0.0f;
#pragma unroll
      for (int c2 = 0; c2 < 7; ++c2) s = fmaf(qk[c2], r[c2], s);
      sc[j] = s;
      m = fmaxf(m, s);
    }
    float sum = 0.0f;
    float wsum[7] = {0, 0, 0, 0, 0, 0, 0};
#pragma unroll
    for (int j = 0; j < LQ; ++j) {
      const float p = __expf(sc[j] - m);
      sum += p;
      const float* r = frow + j * 7;
#pragma unroll
      for (int c2 = 0; c2 < 7; ++c2) wsum[c2] = fmaf(p, r[c2], wsum[c2]);
    }
    const float inv = 1.0f / sum;
#pragma unroll
    for (int c = 0; c < 7; ++c) {
      float s = 0.0f;
#pragma unroll
      for (int c2 = 0; c2 < 7; ++c2) s = fmaf(Mh[c * 7 + c2], wsum[c2], s);
      hpart[f][h][c] = s * inv;
    }
  }
  __syncthreads();

  // ---- phase 2b: per-frame epilogue (64 lanes) ----
  if (tid < BF) {
    const int f = tid;
    float v[7];
#pragma unroll
    for (int c = 0; c < 7; ++c)
      v[c] = feas_s[f][c] + hpart[f][0][c] + hpart[f][1][c] + hpart[f][2][c] + hpart[f][3][c];

    float mu = 0.0f;
#pragma unroll
    for (int c = 0; c < 7; ++c) mu += v[c];
    mu *= (1.0f / 7.0f);
    float var = 0.0f;
#pragma unroll
    for (int c = 0; c < 7; ++c) { const float d = v[c] - mu; var = fmaf(d, d, var); }
    var *= (1.0f / 7.0f);
    float rs = rsqrtf(var + 1e-5f);
    float o1[7];
#pragma unroll
    for (int c = 0; c < 7; ++c) o1[c] = (v[c] - mu) * rs * ln1g[c] + ln1b[c];

    float ff[7] = {0, 0, 0, 0, 0, 0, 0};
    for (int k = 0; k < 64; ++k) {
      float hk = 0.0f;
#pragma unroll
      for (int c = 0; c < 7; ++c) hk = fmaf(W1[k * 7 + c], o1[c], hk);
      hk = fmaxf(hk, 0.0f);
#pragma unroll
      for (int c = 0; c < 7; ++c) ff[c] = fmaf(W2[c * 64 + k], hk, ff[c]);
    }

#pragma unroll
    for (int c = 0; c < 7; ++c) v[c] = ff[c] + o1[c];
    mu = 0.0f;
#pragma unroll
    for (int c = 0; c < 7; ++c) mu += v[c];
    mu *= (1.0f / 7.0f);
    var = 0.0f;
#pragma unroll
    for (int c = 0; c < 7; ++c) { const float d = v[c] - mu; var = fmaf(d, d, var); }
    var *= (1.0f / 7.0f);
    rs = rsqrtf(var + 1e-5f);
    const int t = t0 + f;
#pragma unroll
    for (int c = 0; c < 7; ++c)
      out[(size_t)t * 7 + c] = (v[c] - mu) * rs * ln2g[c] + ln2b[c];
  }
}

// ---------------------------------------------------------------------------
extern "C" void kernel_launch(void* const* d_in, const int* in_sizes, int n_in,
                              void* d_out, int out_size, void* d_ws, size_t ws_size,
                              hipStream_t stream) {
  const float* x    = (const float*)d_in[0];   // (1, 7, T)
  const float* lf   = (const float*)d_in[1];   // (1, T, 2048)
  const float* Wfc  = (const float*)d_in[2];   // (7, 2048)
  const float* Wq   = (const float*)d_in[3];   // (256, 7)
  const float* Wk   = (const float*)d_in[4];   // (256, 7)
  const float* Wv   = (const float*)d_in[5];   // (256, 7)
  const float* Wo   = (const float*)d_in[6];   // (7, 256)
  const float* ln1g = (const float*)d_in[7];
  const float* ln1b = (const float*)d_in[8];
  const float* W1   = (const float*)d_in[9];   // (64, 7)
  const float* W2   = (const float*)d_in[10];  // (7, 64)
  const float* ln2g = (const float*)d_in[11];
  const float* ln2b = (const float*)d_in[12];
  float* out = (float*)d_out;

  float* AM = (float*)d_ws;   // 392 floats

  setup_kernel<<<1, 448, 0, stream>>>(Wq, Wk, Wv, Wo, AM);
  // feas written into `out` (scratch); attn_kernel rewrites it in place.
  feas_kernel<<<T_FRAMES / FPB_A, 256, 0, stream>>>(lf, Wfc, out);
  attn_kernel<<<T_FRAMES / BF, 256, 0, stream>>>(
      x, out, AM, W1, W2, ln1g, ln1b, ln2g, ln2b, out);
}

// Round 2
// 268.741 us; speedup vs baseline: 1.0318x; 1.0318x over previous
//
#include <hip/hip_runtime.h>
#include <math.h>

#define T_FRAMES 16384
#define FDIM 2048
#define LQ 30
#define BF 32      // frames per block
#define ITERS 4    // 4 waves x 2 frames x 4 iters = 32 frames

// ---------------------------------------------------------------------------
// Kernel 0: precompute per-head 7x7 bilinear forms
//   A_h[c][c2] = sum_d W_q[h*64+d][c] * W_k[h*64+d][c2]
//   M_h[c][c2] = sum_d W_o[c][h*64+d] * W_v[h*64+d][c2]
// AM layout: [0..195] = A (h*49 + c*7 + c2), [196..391] = M
// ---------------------------------------------------------------------------
__global__ __launch_bounds__(448) void setup_kernel(
    const float* __restrict__ Wq, const float* __restrict__ Wk,
    const float* __restrict__ Wv, const float* __restrict__ Wo,
    float* __restrict__ AM) {
  const int e = threadIdx.x;
  if (e >= 392) return;
  const int which = e / 196;
  const int r = e % 196;
  const int h = r / 49;
  const int rr = r % 49;
  const int c = rr / 7;
  const int c2 = rr % 7;
  float s = 0.0f;
  if (which == 0) {
    for (int d = 0; d < 64; ++d)
      s = fmaf(Wq[(h * 64 + d) * 7 + c], Wk[(h * 64 + d) * 7 + c2], s);
  } else {
    for (int d = 0; d < 64; ++d)
      s = fmaf(Wo[c * 256 + h * 64 + d], Wv[(h * 64 + d) * 7 + c2], s);
  }
  AM[e] = s;
}

// ---------------------------------------------------------------------------
// Fused kernel, v3. Per block of 32 frames:
//   stage: Wfc (56 KB!) + AM + x-window into LDS, once per block
//   phase 1 (x4 iters): wave w -> 2 frames; burst-load both lf rows
//     (16 float4 in flight), FMA against LDS-resident Wfc, shuffle-reduce,
//     tanh -> feas_s
//   phase 2a: (frame, head) lanes -> collapsed 7x7 attention
//   phase 2b: per-frame LN1 + FFN + LN2 -> out
// Key change vs v2: Wfc was re-read from L2 by EVERY wave (458 MB of
// latency-exposed traffic chip-wide) -- now read once per block from LDS.
// ---------------------------------------------------------------------------
__global__ __launch_bounds__(256) void fused_kernel(
    const float* __restrict__ lf,    // (T, 2048)
    const float* __restrict__ Wfc,   // (7, 2048)
    const float* __restrict__ x,     // (7, T)
    const float* __restrict__ AM,    // 392
    const float* __restrict__ W1,    // (64, 7)
    const float* __restrict__ W2,    // (7, 64)
    const float* __restrict__ ln1g, const float* __restrict__ ln1b,
    const float* __restrict__ ln2g, const float* __restrict__ ln2b,
    float* __restrict__ out) {       // (T, 7)
  __shared__ float wfc_s[7 * FDIM];            // 56 KB
  __shared__ float AM_s[392];
  __shared__ float ft[(BF + LQ - 1) * 7];      // 61 rows x 7
  __shared__ float feas_s[BF][7];
  __shared__ float hpart[BF][4][7];

  const int tid = threadIdx.x;
  const int lane = tid & 63;
  const int wave = tid >> 6;
  const int t0 = blockIdx.x * BF;

  // ---- stage Wfc (3584 float4, coalesced, 14 per thread) ----
  {
    const float4* src = (const float4*)Wfc;
    float4* dst = (float4*)wfc_s;
    for (int i = tid; i < (7 * FDIM) / 4; i += 256) dst[i] = src[i];
  }
  for (int i = tid; i < 392; i += 256) AM_s[i] = AM[i];
  for (int i = tid; i < (BF + LQ - 1) * 7; i += 256) {
    const int row = i / 7, c = i % 7;
    const int s = t0 - (LQ - 1) + row;
    ft[i] = (s >= 0) ? x[c * T_FRAMES + s] : 0.0f;
  }
  __syncthreads();

  // ---- phase 1: feas for 2 frames per wave, 4 iterations ----
  for (int it = 0; it < ITERS; ++it) {
    const int fl = it * 8 + wave * 2;          // local frame index
    const float* lfp = lf + (size_t)(t0 + fl) * FDIM + lane * 4;

    // burst: 16 independent float4 loads (16 KB/wave in flight)
    float4 a0[8], a1[8];
#pragma unroll
    for (int ch = 0; ch < 8; ++ch) a0[ch] = *(const float4*)(lfp + ch * 256);
#pragma unroll
    for (int ch = 0; ch < 8; ++ch) a1[ch] = *(const float4*)(lfp + FDIM + ch * 256);

    float acc0[7] = {0, 0, 0, 0, 0, 0, 0};
    float acc1[7] = {0, 0, 0, 0, 0, 0, 0};
#pragma unroll
    for (int ch = 0; ch < 8; ++ch) {
#pragma unroll
      for (int c = 0; c < 7; ++c) {
        const float4 w = *(const float4*)(&wfc_s[c * FDIM + ch * 256 + lane * 4]);
        acc0[c] = fmaf(a0[ch].x, w.x, fmaf(a0[ch].y, w.y,
                  fmaf(a0[ch].z, w.z, fmaf(a0[ch].w, w.w, acc0[c]))));
        acc1[c] = fmaf(a1[ch].x, w.x, fmaf(a1[ch].y, w.y,
                  fmaf(a1[ch].z, w.z, fmaf(a1[ch].w, w.w, acc1[c]))));
      }
    }

#pragma unroll
    for (int c = 0; c < 7; ++c) {
      float v0 = acc0[c];
      float v1 = acc1[c];
#pragma unroll
      for (int off = 32; off > 0; off >>= 1) {
        v0 += __shfl_down(v0, off, 64);
        v1 += __shfl_down(v1, off, 64);
      }
      if (lane == 0) {
        feas_s[fl][c]     = tanhf(v0);
        feas_s[fl + 1][c] = tanhf(v1);
      }
    }
  }
  __syncthreads();

  // ---- phase 2a: (frame, head) lanes, 128 of 256 active ----
  if (tid < BF * 4) {
    const int f = tid >> 2;   // local frame
    const int h = tid & 3;    // head
    float fe[7];
#pragma unroll
    for (int c = 0; c < 7; ++c) fe[c] = feas_s[f][c];

    const float* Ah = AM_s + h * 49;
    const float* Mh = AM_s + 196 + h * 49;
    float qk[7];
#pragma unroll
    for (int c2 = 0; c2 < 7; ++c2) {
      float s = 0.0f;
#pragma unroll
      for (int c = 0; c < 7; ++c) s = fmaf(fe[c], Ah[c * 7 + c2], s);
      qk[c2] = s * 0.125f;
    }
    const float* frow = &ft[f * 7];
    float sc[LQ];
    float m = -1e30f;
#pragma unroll
    for (int j = 0; j < LQ; ++j) {
      const float* r = frow + j * 7;
      float s = 0.0f;
#pragma unroll
      for (int c2 = 0; c2 < 7; ++c2) s = fmaf(qk[c2], r[c2], s);
      sc[j] = s;
      m = fmaxf(m, s);
    }
    float sum = 0.0f;
    float wsum[7] = {0, 0, 0, 0, 0, 0, 0};
#pragma unroll
    for (int j = 0; j < LQ; ++j) {
      const float p = __expf(sc[j] - m);
      sum += p;
      const float* r = frow + j * 7;
#pragma unroll
      for (int c2 = 0; c2 < 7; ++c2) wsum[c2] = fmaf(p, r[c2], wsum[c2]);
    }
    const float inv = 1.0f / sum;
#pragma unroll
    for (int c = 0; c < 7; ++c) {
      float s = 0.0f;
#pragma unroll
      for (int c2 = 0; c2 < 7; ++c2) s = fmaf(Mh[c * 7 + c2], wsum[c2], s);
      hpart[f][h][c] = s * inv;
    }
  }
  __syncthreads();

  // ---- phase 2b: per-frame epilogue ----
  if (tid < BF) {
    const int f = tid;
    float v[7];
#pragma unroll
    for (int c = 0; c < 7; ++c)
      v[c] = feas_s[f][c] + hpart[f][0][c] + hpart[f][1][c] + hpart[f][2][c] + hpart[f][3][c];

    float mu = 0.0f;
#pragma unroll
    for (int c = 0; c < 7; ++c) mu += v[c];
    mu *= (1.0f / 7.0f);
    float var = 0.0f;
#pragma unroll
    for (int c = 0; c < 7; ++c) { const float d = v[c] - mu; var = fmaf(d, d, var); }
    var *= (1.0f / 7.0f);
    float rs = rsqrtf(var + 1e-5f);
    float o1[7];
#pragma unroll
    for (int c = 0; c < 7; ++c) o1[c] = (v[c] - mu) * rs * ln1g[c] + ln1b[c];

    float ff[7] = {0, 0, 0, 0, 0, 0, 0};
    for (int k = 0; k < 64; ++k) {
      float hk = 0.0f;
#pragma unroll
      for (int c = 0; c < 7; ++c) hk = fmaf(W1[k * 7 + c], o1[c], hk);
      hk = fmaxf(hk, 0.0f);
#pragma unroll
      for (int c = 0; c < 7; ++c) ff[c] = fmaf(W2[c * 64 + k], hk, ff[c]);
    }

#pragma unroll
    for (int c = 0; c < 7; ++c) v[c] = ff[c] + o1[c];
    mu = 0.0f;
#pragma unroll
    for (int c = 0; c < 7; ++c) mu += v[c];
    mu *= (1.0f / 7.0f);
    var = 0.0f;
#pragma unroll
    for (int c = 0; c < 7; ++c) { const float d = v[c] - mu; var = fmaf(d, d, var); }
    var *= (1.0f / 7.0f);
    rs = rsqrtf(var + 1e-5f);
    const int t = t0 + f;
#pragma unroll
    for (int c = 0; c < 7; ++c)
      out[(size_t)t * 7 + c] = (v[c] - mu) * rs * ln2g[c] + ln2b[c];
  }
}

// ---------------------------------------------------------------------------
extern "C" void kernel_launch(void* const* d_in, const int* in_sizes, int n_in,
                              void* d_out, int out_size, void* d_ws, size_t ws_size,
                              hipStream_t stream) {
  const float* x    = (const float*)d_in[0];   // (1, 7, T)
  const float* lf   = (const float*)d_in[1];   // (1, T, 2048)
  const float* Wfc  = (const float*)d_in[2];   // (7, 2048)
  const float* Wq   = (const float*)d_in[3];   // (256, 7)
  const float* Wk   = (const float*)d_in[4];   // (256, 7)
  const float* Wv   = (const float*)d_in[5];   // (256, 7)
  const float* Wo   = (const float*)d_in[6];   // (7, 256)
  const float* ln1g = (const float*)d_in[7];
  const float* ln1b = (const float*)d_in[8];
  const float* W1   = (const float*)d_in[9];   // (64, 7)
  const float* W2   = (const float*)d_in[10];  // (7, 64)
  const float* ln2g = (const float*)d_in[11];
  const float* ln2b = (const float*)d_in[12];
  float* out = (float*)d_out;

  float* AM = (float*)d_ws;   // 392 floats

  setup_kernel<<<1, 448, 0, stream>>>(Wq, Wk, Wv, Wo, AM);
  fused_kernel<<<T_FRAMES / BF, 256, 0, stream>>>(
      lf, Wfc, x, AM, W1, W2, ln1g, ln1b, ln2g, ln2b, out);
}

// Round 3
// 245.897 us; speedup vs baseline: 1.1277x; 1.0929x over previous
//
#include <hip/hip_runtime.h>
#include <math.h>

#define T_FRAMES 16384
#define FDIM 2048
#define LQ 30
#define FR 4          // frames per wave (feas kernel)
#define BF 64         // frames per block (attn kernel)

// ---------------------------------------------------------------------------
// Kernel 0: precompute per-head 7x7 bilinear forms
//   A_h[c][c2] = sum_d W_q[h*64+d][c] * W_k[h*64+d][c2]
//   M_h[c][c2] = sum_d W_o[c][h*64+d] * W_v[h*64+d][c2]
// AM layout: [0..195] = A (h*49 + c*7 + c2), [196..391] = M
// ---------------------------------------------------------------------------
__global__ __launch_bounds__(448) void setup_kernel(
    const float* __restrict__ Wq, const float* __restrict__ Wk,
    const float* __restrict__ Wv, const float* __restrict__ Wo,
    float* __restrict__ AM) {
  const int e = threadIdx.x;
  if (e >= 392) return;
  const int which = e / 196;
  const int r = e % 196;
  const int h = r / 49;
  const int rr = r % 49;
  const int c = rr / 7;
  const int c2 = rr % 7;
  float s = 0.0f;
  if (which == 0) {
    for (int d = 0; d < 64; ++d)
      s = fmaf(Wq[(h * 64 + d) * 7 + c], Wk[(h * 64 + d) * 7 + c2], s);
  } else {
    for (int d = 0; d < 64; ++d)
      s = fmaf(Wo[c * 256 + h * 64 + d], Wv[(h * 64 + d) * 7 + c2], s);
  }
  AM[e] = s;
}

// ---------------------------------------------------------------------------
// Kernel 1 (v4): feas[t][c] = tanh(lf[t] . Wfc[c])
// OCCUPANCY-FIRST design: no LDS, no burst arrays, VGPR capped at 128 via
// __launch_bounds__(256,4) -> >=16 waves/CU, whole grid co-resident.
// Each wave owns 4 frames (amortizes the L2-hot Wfc reads 4x).
// Butterfly reduce so all 64 lanes finish with sums; 28 lanes store in
// parallel (no serial lane-0 tanh tail).
// ---------------------------------------------------------------------------
__global__ __launch_bounds__(256, 4) void feas_kernel(
    const float* __restrict__ lf,    // (T, 2048)
    const float* __restrict__ Wfc,   // (7, 2048)
    float* __restrict__ feas) {      // (T, 7)
  const int tid = threadIdx.x;
  const int lane = tid & 63;
  const int wave = tid >> 6;
  const int gw = blockIdx.x * 4 + wave;    // global wave id
  const int t0 = gw * FR;                  // first of 4 frames
  const float* lfp = lf + (size_t)t0 * FDIM + lane * 4;

  float acc[FR][7];
#pragma unroll
  for (int fr = 0; fr < FR; ++fr)
#pragma unroll
    for (int c = 0; c < 7; ++c) acc[fr][c] = 0.0f;

#pragma unroll
  for (int ch = 0; ch < 8; ++ch) {
    float4 a[FR];
#pragma unroll
    for (int fr = 0; fr < FR; ++fr)
      a[fr] = *(const float4*)(lfp + fr * FDIM + ch * 256);
    float4 w[7];
#pragma unroll
    for (int c = 0; c < 7; ++c)
      w[c] = *(const float4*)(Wfc + c * FDIM + ch * 256 + lane * 4);
#pragma unroll
    for (int fr = 0; fr < FR; ++fr)
#pragma unroll
      for (int c = 0; c < 7; ++c)
        acc[fr][c] = fmaf(a[fr].x, w[c].x, fmaf(a[fr].y, w[c].y,
                     fmaf(a[fr].z, w[c].z, fmaf(a[fr].w, w[c].w, acc[fr][c]))));
  }

  // full-wave butterfly: every lane ends with the total for every acc
#pragma unroll
  for (int fr = 0; fr < FR; ++fr)
#pragma unroll
    for (int c = 0; c < 7; ++c)
#pragma unroll
      for (int off = 1; off < 64; off <<= 1)
        acc[fr][c] += __shfl_xor(acc[fr][c], off, 64);

  // lane l < 28 stores tanh of acc[l/7][l%7]  (static select chain, no
  // runtime-indexed register array -> stays in VGPRs)
  float v = acc[0][0];
#pragma unroll
  for (int fr = 0; fr < FR; ++fr)
#pragma unroll
    for (int c = 0; c < 7; ++c)
      if (lane == fr * 7 + c) v = acc[fr][c];
  if (lane < FR * 7) feas[(size_t)t0 * 7 + lane] = tanhf(v);
}

// ---------------------------------------------------------------------------
// Kernel 2: attention + FFN + LNs (unchanged from R1 -- verified, cheap).
// 64 frames/block; 2a uses all 256 threads; reads feas from `out`,
// overwrites in place (LDS-staged before the barrier).
// ---------------------------------------------------------------------------
__global__ __launch_bounds__(256) void attn_kernel(
    const float* __restrict__ x,       // (7, T)
    const float* __restrict__ feas_g,  // (T, 7)  == out
    const float* __restrict__ AM,      // 392
    const float* __restrict__ W1,      // (64, 7)
    const float* __restrict__ W2,      // (7, 64)
    const float* __restrict__ ln1g, const float* __restrict__ ln1b,
    const float* __restrict__ ln2g, const float* __restrict__ ln2b,
    float* __restrict__ out) {         // (T, 7)
  __shared__ float AM_s[392];
  __shared__ float ft[(BF + LQ - 1) * 7];
  __shared__ float feas_s[BF][7];
  __shared__ float hpart[BF][4][7];

  const int tid = threadIdx.x;
  const int t0 = blockIdx.x * BF;

  for (int i = tid; i < 392; i += 256) AM_s[i] = AM[i];
  for (int i = tid; i < (BF + LQ - 1) * 7; i += 256) {
    const int row = i / 7, c = i % 7;
    const int s = t0 - (LQ - 1) + row;
    ft[i] = (s >= 0) ? x[c * T_FRAMES + s] : 0.0f;
  }
  for (int i = tid; i < BF * 7; i += 256)
    feas_s[i / 7][i % 7] = feas_g[(size_t)t0 * 7 + i];
  __syncthreads();

  // ---- phase 2a: (frame, head) per thread, 256/256 active ----
  {
    const int f = tid >> 2;
    const int h = tid & 3;
    float fe[7];
#pragma unroll
    for (int c = 0; c < 7; ++c) fe[c] = feas_s[f][c];

    const float* Ah = AM_s + h * 49;
    const float* Mh = AM_s + 196 + h * 49;
    float qk[7];
#pragma unroll
    for (int c2 = 0; c2 < 7; ++c2) {
      float s = 0.0f;
#pragma unroll
      for (int c = 0; c < 7; ++c) s = fmaf(fe[c], Ah[c * 7 + c2], s);
      qk[c2] = s * 0.125f;
    }
    const float* frow = &ft[f * 7];
    float sc[LQ];
    float m = -1e30f;
#pragma unroll
    for (int j = 0; j < LQ; ++j) {
      const float* r = frow + j * 7;
      float s = 0.0f;
#pragma unroll
      for (int c2 = 0; c2 < 7; ++c2) s = fmaf(qk[c2], r[c2], s);
      sc[j] = s;
      m = fmaxf(m, s);
    }
    float sum = 0.0f;
    float wsum[7] = {0, 0, 0, 0, 0, 0, 0};
#pragma unroll
    for (int j = 0; j < LQ; ++j) {
      const float p = __expf(sc[j] - m);
      sum += p;
      const float* r = frow + j * 7;
#pragma unroll
      for (int c2 = 0; c2 < 7; ++c2) wsum[c2] = fmaf(p, r[c2], wsum[c2]);
    }
    const float inv = 1.0f / sum;
#pragma unroll
    for (int c = 0; c < 7; ++c) {
      float s = 0.0f;
#pragma unroll
      for (int c2 = 0; c2 < 7; ++c2) s = fmaf(Mh[c * 7 + c2], wsum[c2], s);
      hpart[f][h][c] = s * inv;
    }
  }
  __syncthreads();

  // ---- phase 2b: per-frame epilogue ----
  if (tid < BF) {
    const int f = tid;
    float v[7];
#pragma unroll
    for (int c = 0; c < 7; ++c)
      v[c] = feas_s[f][c] + hpart[f][0][c] + hpart[f][1][c] + hpart[f][2][c] + hpart[f][3][c];

    float mu = 0.0f;
#pragma unroll
    for (int c = 0; c < 7; ++c) mu += v[c];
    mu *= (1.0f / 7.0f);
    float var = 0.0f;
#pragma unroll
    for (int c = 0; c < 7; ++c) { const float d = v[c] - mu; var = fmaf(d, d, var); }
    var *= (1.0f / 7.0f);
    float rs = rsqrtf(var + 1e-5f);
    float o1[7];
#pragma unroll
    for (int c = 0; c < 7; ++c) o1[c] = (v[c] - mu) * rs * ln1g[c] + ln1b[c];

    float ff[7] = {0, 0, 0, 0, 0, 0, 0};
    for (int k = 0; k < 64; ++k) {
      float hk = 0.0f;
#pragma unroll
      for (int c = 0; c < 7; ++c) hk = fmaf(W1[k * 7 + c], o1[c], hk);
      hk = fmaxf(hk, 0.0f);
#pragma unroll
      for (int c = 0; c < 7; ++c) ff[c] = fmaf(W2[c * 64 + k], hk, ff[c]);
    }

#pragma unroll
    for (int c = 0; c < 7; ++c) v[c] = ff[c] + o1[c];
    mu = 0.0f;
#pragma unroll
    for (int c = 0; c < 7; ++c) mu += v[c];
    mu *= (1.0f / 7.0f);
    var = 0.0f;
#pragma unroll
    for (int c = 0; c < 7; ++c) { const float d = v[c] - mu; var = fmaf(d, d, var); }
    var *= (1.0f / 7.0f);
    rs = rsqrtf(var + 1e-5f);
    const int t = t0 + f;
#pragma unroll
    for (int c = 0; c < 7; ++c)
      out[(size_t)t * 7 + c] = (v[c] - mu) * rs * ln2g[c] + ln2b[c];
  }
}

// ---------------------------------------------------------------------------
extern "C" void kernel_launch(void* const* d_in, const int* in_sizes, int n_in,
                              void* d_out, int out_size, void* d_ws, size_t ws_size,
                              hipStream_t stream) {
  const float* x    = (const float*)d_in[0];   // (1, 7, T)
  const float* lf   = (const float*)d_in[1];   // (1, T, 2048)
  const float* Wfc  = (const float*)d_in[2];   // (7, 2048)
  const float* Wq   = (const float*)d_in[3];   // (256, 7)
  const float* Wk   = (const float*)d_in[4];   // (256, 7)
  const float* Wv   = (const float*)d_in[5];   // (256, 7)
  const float* Wo   = (const float*)d_in[6];   // (7, 256)
  const float* ln1g = (const float*)d_in[7];
  const float* ln1b = (const float*)d_in[8];
  const float* W1   = (const float*)d_in[9];   // (64, 7)
  const float* W2   = (const float*)d_in[10];  // (7, 64)
  const float* ln2g = (const float*)d_in[11];
  const float* ln2b = (const float*)d_in[12];
  float* out = (float*)d_out;

  float* AM = (float*)d_ws;   // 392 floats

  setup_kernel<<<1, 448, 0, stream>>>(Wq, Wk, Wv, Wo, AM);
  // feas written into `out` (scratch); attn_kernel rewrites it in place.
  feas_kernel<<<T_FRAMES / (FR * 4), 256, 0, stream>>>(lf, Wfc, out);
  attn_kernel<<<T_FRAMES / BF, 256, 0, stream>>>(
      x, out, AM, W1, W2, ln1g, ln1b, ln2g, ln2b, out);
}